// Round 5
// baseline (95.698 us; speedup 1.0000x reference)
//
#include <hip/hip_runtime.h>

// Adaptive mean thresholding: out = (x > mean11x11(x) - 2) ? 0 : 255, replicate border.
// BIT-EXACT contract (verified absmax=0.0 in rounds 3-4): vertical 11-tap f32 FMA
// chain (ascending row order, weight (float)(1.0/11.0)), rounded to f32; then
// horizontal 11-tap f32 FMA chain (ascending col order); thresh = m - 2.0f;
// decision x > thresh. Replicate-border mv values are bitwise duplicates of the
// edge mv, so halo is synthesized by duplication, never recomputed differently.
//
// R5: wave-per-row, register-only. 64 lanes x 8 cols = 512 cols. Horizontal halo
// via 10 __shfl from neighbor lanes (no LDS, no barriers, no bank conflicts).
// Vertical 11-row ring fully in registers; RPB=16 row loop fully unrolled so all
// ring indices are compile-time constants. NT stores keep L3 for the input.

constexpr int W   = 512;
constexpr int H   = 512;
constexpr int PAD = 5;
constexpr int KS  = 11;
constexpr int CPT = 8;           // columns per lane
constexpr int TPB = 64;          // one wave per block
constexpr int RPB = 16;          // output rows per wave
constexpr int STRIPS = H / RPB;  // 32 strips per image

typedef float f32x4 __attribute__((ext_vector_type(4)));

__global__ __launch_bounds__(TPB)
void AdaptiveThresholding_57904749085171_kernel(const float* __restrict__ x,
                                                float* __restrict__ out)
{
    const int l     = (int)threadIdx.x;          // lane 0..63
    const int strip = (int)blockIdx.x;
    const int img   = strip / STRIPS;
    const int y0    = (strip % STRIPS) * RPB;
    const size_t ioff = (size_t)img * (size_t)(W * H);
    const float* __restrict__ xi = x + ioff;
    float* __restrict__ oi = out + ioff;
    const int cbase = l * CPT;
    const float wv = (float)(1.0 / 11.0);

    float ring[KS][CPT];   // virtual rows, slot s holds row r with (r-(y0-5))%11 == s

    // ---- prologue: virtual rows y0-5 .. y0+4 -> slots 0..9 ----
    #pragma unroll
    for (int j = 0; j < KS - 1; ++j) {
        int row = y0 - PAD + j;
        row = row < 0 ? 0 : (row >= H ? H - 1 : row);
        const f32x4* p = (const f32x4*)(xi + (size_t)row * W + cbase);
        const f32x4 a = p[0], b = p[1];
        #pragma unroll
        for (int i = 0; i < 4; ++i) { ring[j][i] = a[i]; ring[j][4 + i] = b[i]; }
    }

    #pragma unroll
    for (int k = 0; k < RPB; ++k) {
        // ---- load new virtual row y0+5+k into slot (10+k)%11 ----
        {
            int row = y0 + PAD + k;
            row = row >= H ? H - 1 : row;
            const f32x4* p = (const f32x4*)(xi + (size_t)row * W + cbase);
            const f32x4 a = p[0], b = p[1];
            #pragma unroll
            for (int i = 0; i < 4; ++i) {
                ring[(10 + k) % KS][i]     = a[i];
                ring[(10 + k) % KS][4 + i] = b[i];
            }
        }

        // ---- vertical f32 FMA chains, ascending row order ----
        float a[CPT];
        #pragma unroll
        for (int i = 0; i < CPT; ++i) {
            float s = 0.0f;
            #pragma unroll
            for (int d = 0; d < KS; ++d) s = fmaf(ring[(k + d) % KS][i], wv, s);
            a[i] = s;
        }

        // ---- halo mv values from neighbor lanes (replicate at image edges) ----
        float z[CPT + 2 * PAD];   // z[j] = mv[cbase - 5 + j]
        #pragma unroll
        for (int q = 0; q < PAD; ++q) {
            const float vL = __shfl(a[3 + q], l - 1, 64);   // left lane's cols 3..7
            z[q] = (l == 0) ? a[0] : vL;                    // mv[<0] == mv[0] bitwise
        }
        #pragma unroll
        for (int i = 0; i < CPT; ++i) z[PAD + i] = a[i];
        #pragma unroll
        for (int q = 0; q < PAD; ++q) {
            const float vR = __shfl(a[q], l + 1, 64);       // right lane's cols 0..4
            z[PAD + CPT + q] = (l == 63) ? a[7] : vR;       // mv[>511] == mv[511]
        }

        // ---- horizontal f32 FMA chains (ascending col order) + decision ----
        float o[CPT];
        #pragma unroll
        for (int i = 0; i < CPT; ++i) {
            float m = 0.0f;
            #pragma unroll
            for (int d = 0; d < KS; ++d) m = fmaf(z[i + d], wv, m);
            const float xv = ring[(k + PAD) % KS][i];       // row y center value
            o[i] = (xv > m - 2.0f) ? 0.0f : 255.0f;
        }

        // ---- non-temporal stores (keep L3 for the input) ----
        f32x4 o0, o1;
        #pragma unroll
        for (int i = 0; i < 4; ++i) { o0[i] = o[i]; o1[i] = o[4 + i]; }
        f32x4* op = (f32x4*)(oi + (size_t)(y0 + k) * W + cbase);
        __builtin_nontemporal_store(o0, op);
        __builtin_nontemporal_store(o1, op + 1);
    }
}

extern "C" void kernel_launch(void* const* d_in, const int* in_sizes, int n_in,
                              void* d_out, int out_size, void* d_ws, size_t ws_size,
                              hipStream_t stream)
{
    const float* x = (const float*)d_in[0];
    float* out = (float*)d_out;
    const int n_imgs = in_sizes[0] / (W * H);   // 128

    dim3 grid(n_imgs * STRIPS);   // 128 * 32 = 4096 waves
    dim3 block(TPB);
    AdaptiveThresholding_57904749085171_kernel<<<grid, block, 0, stream>>>(x, out);
}

// Round 6
// 62.295 us; speedup vs baseline: 1.5362x; 1.5362x over previous
//
#include <hip/hip_runtime.h>

// Adaptive mean thresholding: out = (x > mean11x11(x) - 2) ? 0 : 255, replicate border.
// BIT-EXACT contract (verified absmax=0.0 in rounds 3-5): vertical 11-tap f32 FMA
// chain (ascending row order, weight (float)(1.0/11.0)), rounded to f32; then
// horizontal 11-tap f32 FMA chain (ascending col order); thresh = m - 2.0f;
// decision x > thresh. Replicate-border mv values are bitwise duplicates of the
// edge mv (synthesized by duplication, never recomputed).
//
// R6: R5's wave-autonomous register/shuffle dataflow (no LDS, no barriers, zero
// bank conflicts) but with 4 waves per 256-thread block to restore occupancy
// (R5's 1-wave blocks sat at 28% occupancy -> latency-bound at 11% VALUBusy).
// Waves in a block process 4 ADJACENT strips of the same image (halo rows are
// L2-shared). Plain float4 stores (R5's NT stores amplified WRITE 131->248 MB).

constexpr int W   = 512;
constexpr int H   = 512;
constexpr int PAD = 5;
constexpr int KS  = 11;
constexpr int CPT = 8;           // columns per lane
constexpr int TPB = 256;         // 4 waves per block
constexpr int WPB = 4;           // waves (strips) per block
constexpr int RPB = 16;          // output rows per wave
constexpr int STRIPS = H / RPB;  // 32 strips per image

typedef float f32x4 __attribute__((ext_vector_type(4)));

__global__ __launch_bounds__(TPB)
void AdaptiveThresholding_57904749085171_kernel(const float* __restrict__ x,
                                                float* __restrict__ out)
{
    const int l     = (int)threadIdx.x & 63;                 // lane 0..63
    const int wv_id = (int)threadIdx.x >> 6;                 // wave 0..3
    const int strip = (int)blockIdx.x * WPB + wv_id;         // global strip id
    const int img   = strip / STRIPS;
    const int y0    = (strip % STRIPS) * RPB;
    const size_t ioff = (size_t)img * (size_t)(W * H);
    const float* __restrict__ xi = x + ioff;
    float* __restrict__ oi = out + ioff;
    const int cbase = l * CPT;
    const float wv = (float)(1.0 / 11.0);

    float ring[KS][CPT];   // virtual rows y-5..y+5, slot s = row r with (r-(y0-5))%11 == s

    // ---- prologue: virtual rows y0-5 .. y0+4 -> slots 0..9 ----
    #pragma unroll
    for (int j = 0; j < KS - 1; ++j) {
        int row = y0 - PAD + j;
        row = row < 0 ? 0 : (row >= H ? H - 1 : row);
        const f32x4* p = (const f32x4*)(xi + (size_t)row * W + cbase);
        const f32x4 a = p[0], b = p[1];
        #pragma unroll
        for (int i = 0; i < 4; ++i) { ring[j][i] = a[i]; ring[j][4 + i] = b[i]; }
    }

    #pragma unroll
    for (int k = 0; k < RPB; ++k) {
        // ---- load new virtual row y0+5+k into slot (10+k)%11 (used at tap d=10) ----
        {
            int row = y0 + PAD + k;
            row = row >= H ? H - 1 : row;
            const f32x4* p = (const f32x4*)(xi + (size_t)row * W + cbase);
            const f32x4 a = p[0], b = p[1];
            #pragma unroll
            for (int i = 0; i < 4; ++i) {
                ring[(10 + k) % KS][i]     = a[i];
                ring[(10 + k) % KS][4 + i] = b[i];
            }
        }

        // ---- vertical f32 FMA chains, ascending row order ----
        float a[CPT];
        #pragma unroll
        for (int i = 0; i < CPT; ++i) {
            float s = 0.0f;
            #pragma unroll
            for (int d = 0; d < KS; ++d) s = fmaf(ring[(k + d) % KS][i], wv, s);
            a[i] = s;
        }

        // ---- halo mv values from neighbor lanes (replicate at image edges) ----
        float z[CPT + 2 * PAD];   // z[j] = mv[cbase - 5 + j]
        #pragma unroll
        for (int q = 0; q < PAD; ++q) {
            const float vL = __shfl(a[3 + q], l - 1, 64);   // left lane's cols 3..7
            z[q] = (l == 0) ? a[0] : vL;                    // mv[<0] == mv[0] bitwise
        }
        #pragma unroll
        for (int i = 0; i < CPT; ++i) z[PAD + i] = a[i];
        #pragma unroll
        for (int q = 0; q < PAD; ++q) {
            const float vR = __shfl(a[q], l + 1, 64);       // right lane's cols 0..4
            z[PAD + CPT + q] = (l == 63) ? a[7] : vR;       // mv[>511] == mv[511]
        }

        // ---- horizontal f32 FMA chains (ascending col order) + decision ----
        float o[CPT];
        #pragma unroll
        for (int i = 0; i < CPT; ++i) {
            float m = 0.0f;
            #pragma unroll
            for (int d = 0; d < KS; ++d) m = fmaf(z[i + d], wv, m);
            const float xv = ring[(k + PAD) % KS][i];       // row y center value
            o[i] = (xv > m - 2.0f) ? 0.0f : 255.0f;
        }

        // ---- plain vector stores ----
        f32x4 o0, o1;
        #pragma unroll
        for (int i = 0; i < 4; ++i) { o0[i] = o[i]; o1[i] = o[4 + i]; }
        f32x4* op = (f32x4*)(oi + (size_t)(y0 + k) * W + cbase);
        op[0] = o0;
        op[1] = o1;
    }
}

extern "C" void kernel_launch(void* const* d_in, const int* in_sizes, int n_in,
                              void* d_out, int out_size, void* d_ws, size_t ws_size,
                              hipStream_t stream)
{
    const float* x = (const float*)d_in[0];
    float* out = (float*)d_out;
    const int n_imgs = in_sizes[0] / (W * H);   // 128
    const int n_strips = n_imgs * STRIPS;       // 4096

    dim3 grid(n_strips / WPB);   // 1024 blocks x 4 waves
    dim3 block(TPB);
    AdaptiveThresholding_57904749085171_kernel<<<grid, block, 0, stream>>>(x, out);
}